// Round 14
// baseline (294.303 us; speedup 1.0000x reference)
//
#include <hip/hip_runtime.h>
#include <hip/hip_bf16.h>
#include <math.h>

typedef __hip_bfloat16 bf16;
typedef _Float16 f16;
typedef f16  f16x8  __attribute__((ext_vector_type(8)));
typedef short short8 __attribute__((ext_vector_type(8)));
typedef unsigned short ushort8 __attribute__((ext_vector_type(8)));
typedef float floatx4 __attribute__((ext_vector_type(4)));

#define L_SEQ 4096
#define BATCH 2
#define DIM   96
#define DI    192
#define DS    16
#define HID   192
#define NPOS  (BATCH * L_SEQ)   // 8192
#define NCH   512               // chunks per sequence
#define CHUNK 8                 // L_SEQ / NCH
#define GRP   32                // chunks per p2 group
#define NGRP  (NCH / GRP)       // 16 groups
#define NREC  (2 * BATCH * DI)  // 768 recurrences (dir,b,d)
#define LDBL  40                // padded x_dbl row stride: dt[0:6), B[8:24), C[24:40)
#define LOG2E 1.44269504088896f
#define TP    32                // positions per LN block

__device__ __forceinline__ float silu_f(float x) { return x / (1.f + __expf(-x)); }
__device__ __forceinline__ float softplus_f(float x) {
    return fmaxf(x, 0.f) + __logf(1.f + __expf(-fabsf(x)));
}
__device__ __forceinline__ float b2f(bf16 v) { return __bfloat162float(v); }
__device__ __forceinline__ float us2f(unsigned short u) {
    union { unsigned int i; float f; } cv; cv.i = ((unsigned int)u) << 16; return cv.f;
}

// ---------------------------------------------------------------------------
// K1: fused LN (blocks 0..255) + prep (blocks 256..1005).
// prep: cast GEMM weights fp32->bf16, A2 table, transposed msff dw.
// ---------------------------------------------------------------------------
__global__ void k_ln12_prep(const float* __restrict__ x,
                            const float* __restrict__ ln1w, const float* __restrict__ ln1b,
                            const float* __restrict__ mnw,  const float* __restrict__ mnb,
                            bf16* __restrict__ XNbf,
                            const float* __restrict__ fWin, const float* __restrict__ bWin,
                            const float* __restrict__ fWx,  const float* __restrict__ bWx,
                            const float* __restrict__ Wout, const float* __restrict__ mwin,
                            const float* __restrict__ mwout,
                            const float* __restrict__ fAlog, const float* __restrict__ bAlog,
                            const float* __restrict__ mdw1, const float* __restrict__ mdw2,
                            const float* __restrict__ mdw3,
                            bf16* __restrict__ war, float* __restrict__ a2tab,
                            float* __restrict__ mdwt) {
    if (blockIdx.x >= NPOS / TP) {
        int i = (blockIdx.x - NPOS / TP) * blockDim.x + threadIdx.x;
        if (i < 180480) {
            float v;
            if (i < 36864)        v = fWin[i];
            else if (i < 73728)   v = bWin[i - 36864];
            else if (i < 81024)   v = fWx[i - 73728];
            else if (i < 88320)   v = bWx[i - 81024];
            else if (i < 106752)  v = Wout[i - 88320];
            else if (i < 162048)  v = mwin[i - 106752];
            else                  v = mwout[i - 162048];
            war[i] = __float2bfloat16(v);
        } else if (i < 186624) {
            int j = i - 180480;
            int dir = j / 3072, rem = j % 3072;
            const float* al = dir ? bAlog : fAlog;
            a2tab[j] = -__expf(al[rem]) * LOG2E;
        } else if (i < 191808) {
            int j = i - 186624;
            int cv = j / 1728, rem = j % 1728;
            int tap = rem / 192, c = rem % 192;
            const float* src = (cv == 0) ? mdw1 : (cv == 1) ? mdw2 : mdw3;
            mdwt[j] = src[c * 9 + tap];
        }
        return;
    }
    __shared__ float xt[DIM][TP + 1];
    __shared__ float rs[8][TP], rss[8][TP];
    __shared__ float uu[TP], rr[TP];
    int p0 = blockIdx.x * TP;
    int b = p0 >> 12, l0 = p0 & (L_SEQ - 1);
    int t = threadIdx.x;
    int tg = t >> 5, li = t & 31;

    for (int idx = t; idx < DIM * TP; idx += 256) {
        int c = idx >> 5, q = idx & 31;
        xt[c][q] = x[((size_t)(b * DIM + c)) * L_SEQ + l0 + q];
    }
    __syncthreads();
    {
        float s = 0.f, ss = 0.f;
        for (int c = tg; c < DIM; c += 8) { float v = xt[c][li]; s += v; ss += v * v; }
        rs[tg][li] = s; rss[tg][li] = ss;
    }
    __syncthreads();
    if (t < TP) {
        float s = 0.f, ss = 0.f;
#pragma unroll
        for (int g = 0; g < 8; g++) { s += rs[g][t]; ss += rss[g][t]; }
        float u = s / DIM;
        uu[t] = u; rr[t] = rsqrtf(ss / DIM - u * u + 1e-6f);
    }
    __syncthreads();
    {
        float u = uu[li], r = rr[li];
        float s2 = 0.f, ss2 = 0.f;
        for (int c = tg; c < DIM; c += 8) {
            float tv = ln1w[c] * (xt[c][li] - u) * r + ln1b[c];
            xt[c][li] = tv;
            s2 += tv; ss2 += tv * tv;
        }
        rs[tg][li] = s2; rss[tg][li] = ss2;
    }
    __syncthreads();
    if (t < TP) {
        float s = 0.f, ss = 0.f;
#pragma unroll
        for (int g = 0; g < 8; g++) { s += rs[g][t]; ss += rss[g][t]; }
        float u = s / DIM;
        uu[t] = u; rr[t] = rsqrtf(ss / DIM - u * u + 1e-5f);
    }
    __syncthreads();
    for (int idx = t; idx < DIM * TP; idx += 256) {
        int q = idx / DIM, c = idx % DIM;
        XNbf[(size_t)(p0 + q) * DIM + c] =
            __float2bfloat16((xt[c][q] - uu[q]) * rr[q] * mnw[c] + mnb[c]);
    }
}

// ---------------------------------------------------------------------------
// MFMA NT GEMM, 2-dir batched via blockIdx.z.
// ---------------------------------------------------------------------------
__global__ void mfma_nt_dir(const bf16* __restrict__ A0, const bf16* __restrict__ A1,
                            const bf16* __restrict__ W0, const bf16* __restrict__ W1,
                            void* __restrict__ C0, void* __restrict__ C1,
                            int M, int N, int K, int ldc, int pad6, int obf) {
    int z = blockIdx.z;
    const bf16* A = z ? A1 : A0;
    const bf16* W = z ? W1 : W0;
    void* C = z ? C1 : C0;
    int wave = threadIdx.x >> 6, lane = threadIdx.x & 63;
    int m0 = blockIdx.x * 64 + wave * 16;
    int n0 = blockIdx.y * 64;
    int lm = lane & 15, quad = lane >> 4;
    const short* Ap = (const short*)A + (size_t)(m0 + lm) * K + quad * 8;
    const short* Wp = (const short*)W;
    floatx4 acc[4];
#pragma unroll
    for (int t = 0; t < 4; t++) acc[t] = (floatx4){0.f, 0.f, 0.f, 0.f};
    for (int k0 = 0; k0 < K; k0 += 32) {
        short8 a = *(const short8*)(Ap + k0);
#pragma unroll
        for (int t = 0; t < 4; t++) {
            int n = n0 + t * 16 + lm;
            short8 b = (n < N) ? *(const short8*)(Wp + (size_t)n * K + k0 + quad * 8)
                               : (short8){0,0,0,0,0,0,0,0};
            acc[t] = __builtin_amdgcn_mfma_f32_16x16x32_bf16(a, b, acc[t], 0, 0, 0);
        }
    }
#pragma unroll
    for (int t = 0; t < 4; t++) {
        int n = n0 + t * 16 + lm;
        if (n < N) {
            int nn = (pad6 && n >= 6) ? n + 2 : n;
#pragma unroll
            for (int r = 0; r < 4; r++) {
                int m = m0 + quad * 4 + r;
                if (obf) ((bf16*)C)[(size_t)m * ldc + nn] = __float2bfloat16(acc[t][r]);
                else     ((float*)C)[(size_t)m * ldc + nn] = acc[t][r];
            }
        }
    }
}

// ---------------------------------------------------------------------------
// MFMA NT single-matrix (msff in-projection): C = A @ W^T, bf16 out.
// ---------------------------------------------------------------------------
__global__ void mfma_nt(const bf16* __restrict__ A, const bf16* __restrict__ W,
                        bf16* __restrict__ C, int M, int N, int K, int ldc) {
    int wave = threadIdx.x >> 6, lane = threadIdx.x & 63;
    int m0 = blockIdx.x * 64 + wave * 16;
    int n0 = blockIdx.y * 64;
    int lm = lane & 15, quad = lane >> 4;
    const short* Ap = (const short*)A + (size_t)(m0 + lm) * K + quad * 8;
    const short* Wp = (const short*)W;
    floatx4 acc[4];
#pragma unroll
    for (int t = 0; t < 4; t++) acc[t] = (floatx4){0.f, 0.f, 0.f, 0.f};
    for (int k0 = 0; k0 < K; k0 += 32) {
        short8 a = *(const short8*)(Ap + k0);
#pragma unroll
        for (int t = 0; t < 4; t++) {
            int n = n0 + t * 16 + lm;
            short8 b = (n < N) ? *(const short8*)(Wp + (size_t)n * K + k0 + quad * 8)
                               : (short8){0,0,0,0,0,0,0,0};
            acc[t] = __builtin_amdgcn_mfma_f32_16x16x32_bf16(a, b, acc[t], 0, 0, 0);
        }
    }
#pragma unroll
    for (int t = 0; t < 4; t++) {
        int n = n0 + t * 16 + lm;
        if (n < N) {
#pragma unroll
            for (int r = 0; r < 4; r++) {
                int m = m0 + quad * 4 + r;
                C[(size_t)m * ldc + n] = __float2bfloat16(acc[t][r]);
            }
        }
    }
}

// ---------------------------------------------------------------------------
// Out-projection, dual-A: YO = (Y1+Y2) @ Wout^T, f32 channel-last out.
// ---------------------------------------------------------------------------
__global__ void mfma_out(const bf16* __restrict__ Y1, const bf16* __restrict__ Y2,
                         const bf16* __restrict__ W, float* __restrict__ C,
                         int M, int N, int K, int ldc) {
    int wave = threadIdx.x >> 6, lane = threadIdx.x & 63;
    int m0 = blockIdx.x * 64 + wave * 16;
    int n0 = blockIdx.y * 64;
    int lm = lane & 15, quad = lane >> 4;
    const short* A1p = (const short*)Y1 + (size_t)(m0 + lm) * K + quad * 8;
    const short* A2p = (const short*)Y2 + (size_t)(m0 + lm) * K + quad * 8;
    const short* Wp  = (const short*)W;
    floatx4 acc[4];
#pragma unroll
    for (int t = 0; t < 4; t++) acc[t] = (floatx4){0.f, 0.f, 0.f, 0.f};
    for (int k0 = 0; k0 < K; k0 += 32) {
        short8 a1 = *(const short8*)(A1p + k0);
        short8 a2 = *(const short8*)(A2p + k0);
#pragma unroll
        for (int t = 0; t < 4; t++) {
            int n = n0 + t * 16 + lm;
            short8 b = (n < N) ? *(const short8*)(Wp + (size_t)n * K + k0 + quad * 8)
                               : (short8){0,0,0,0,0,0,0,0};
            acc[t] = __builtin_amdgcn_mfma_f32_16x16x32_bf16(a1, b, acc[t], 0, 0, 0);
            acc[t] = __builtin_amdgcn_mfma_f32_16x16x32_bf16(a2, b, acc[t], 0, 0, 0);
        }
    }
#pragma unroll
    for (int t = 0; t < 4; t++) {
        int n = n0 + t * 16 + lm;
        if (n < N) {
#pragma unroll
            for (int r = 0; r < 4; r++) {
                int m = m0 + quad * 4 + r;
                C[(size_t)m * ldc + n] = acc[t][r];
            }
        }
    }
}

// ---------------------------------------------------------------------------
// msff out-projection + fused final residual (planar f32 out).
// ---------------------------------------------------------------------------
__global__ void mfma_msffout(const bf16* __restrict__ A, const bf16* __restrict__ Bm,
                             const float* __restrict__ XMID, const float* __restrict__ gamma2,
                             float* __restrict__ out, int M, int K) {
    int wave = threadIdx.x >> 6, lane = threadIdx.x & 63;
    int m0 = blockIdx.x * 64 + wave * 16;
    int n0 = blockIdx.y * 64;
    int lm = lane & 15, quad = lane >> 4;
    int am = m0 + lm;
    bool aval = am < M;
    const short* Ap = (const short*)A + (size_t)am * K + quad * 8;
    const short* Bp = (const short*)Bm;
    floatx4 acc[4];
#pragma unroll
    for (int t = 0; t < 4; t++) acc[t] = (floatx4){0.f, 0.f, 0.f, 0.f};
    for (int k0 = 0; k0 < K; k0 += 32) {
        short8 a = aval ? *(const short8*)(Ap + k0) : (short8){0,0,0,0,0,0,0,0};
#pragma unroll
        for (int t = 0; t < 4; t++) {
            int n = n0 + t * 16 + lm;
            short8 b = *(const short8*)(Bp + (size_t)n * K + k0 + quad * 8);
            acc[t] = __builtin_amdgcn_mfma_f32_16x16x32_bf16(a, b, acc[t], 0, 0, 0);
        }
    }
#pragma unroll
    for (int t = 0; t < 4; t++) {
        int n = n0 + t * 16 + lm;
        int b = n >> 12, l = n & (L_SEQ - 1);
#pragma unroll
        for (int r = 0; r < 4; r++) {
            int m = m0 + quad * 4 + r;
            if (m < M) {
                size_t idx = ((size_t)(b * M + m)) * L_SEQ + l;
                out[idx] = XMID[idx] + gamma2[m] * acc[t][r];
            }
        }
    }
}

// ---------------------------------------------------------------------------
// K3: dwconv1d k=4 + bias + silu, vectorized 8 channels/thread.
// ---------------------------------------------------------------------------
__global__ void k_conv_v(const bf16* __restrict__ XZF, const bf16* __restrict__ XZB,
                         const float* __restrict__ fw, const float* __restrict__ fb,
                         const float* __restrict__ bw, const float* __restrict__ bb,
                         bf16* __restrict__ XSF, bf16* __restrict__ XSB) {
    int dirb = blockIdx.y;
    int i = blockIdx.x * blockDim.x + threadIdx.x;   // NPOS*24
    int dg = i % 24;
    int p = i / 24;
    int b = p >> 12, l = p & (L_SEQ - 1);
    int d0 = dg * 8;
    const bf16* XZ = dirb ? XZB : XZF;
    const float* cw = dirb ? bw : fw;
    const float* cb = dirb ? bb : fb;

    float4 w[8];
#pragma unroll
    for (int j = 0; j < 8; j++) w[j] = *(const float4*)(cw + (d0 + j) * 4);
    float acc[8];
#pragma unroll
    for (int j = 0; j < 8; j++) acc[j] = cb[d0 + j];

#pragma unroll
    for (int k = 0; k < 4; k++) {
        int ls = dirb ? (l + 3 - k) : (l - 3 + k);
        if (ls >= 0 && ls < L_SEQ) {
            ushort8 xv = *(const ushort8*)((const unsigned short*)XZ +
                           ((size_t)(b * L_SEQ + ls)) * 384 + d0);
#pragma unroll
            for (int j = 0; j < 8; j++) {
                float wk = (k == 0) ? w[j].x : (k == 1) ? w[j].y : (k == 2) ? w[j].z : w[j].w;
                acc[j] += wk * us2f(xv[j]);
            }
        }
    }
    ushort8 ov;
#pragma unroll
    for (int j = 0; j < 8; j++) {
        bf16 t = __float2bfloat16(silu_f(acc[j]));
        ov[j] = *(unsigned short*)&t;
    }
    *(ushort8*)((unsigned short*)(dirb ? XSB : XSF) + (size_t)p * DI + d0) = ov;
}

// ---------------------------------------------------------------------------
// Chunked parallel scan, CHUNK=8, NCH=512, A2 table-driven, P/Q fp16.
// Main loops fully unrolled so the compiler can software-pipeline the loads.
// ---------------------------------------------------------------------------
__global__ void k_scan_p1(const float* __restrict__ DBLF, const float* __restrict__ DBLB,
                          const bf16* __restrict__ XSF,  const bf16* __restrict__ XSB,
                          const float* __restrict__ fWdt, const float* __restrict__ fbdt,
                          const float* __restrict__ bWdt, const float* __restrict__ bbdt,
                          const float* __restrict__ a2tab,
                          f16* __restrict__ P, f16* __restrict__ Q) {
    int t = blockIdx.x * blockDim.x + threadIdx.x;   // 393216
    int d = t % DI;
    int g = t / DI;                                   // 0..2047
    int chunk = g & (NCH - 1);
    int dirb = g >> 9;
    int b = dirb & 1, dir = dirb >> 1;

    const float* DBL = dir ? DBLB : DBLF;
    const bf16*  XS  = dir ? XSB  : XSF;
    const float* wdt = (dir ? bWdt : fWdt) + d * 6;
    float bdtv = (dir ? bbdt : fbdt)[d];

    float wd[6];
#pragma unroll
    for (int r = 0; r < 6; r++) wd[r] = wdt[r];
    const float* a2p = a2tab + (dir * DI + d) * 16;
    float A2[16], h[16];
#pragma unroll
    for (int v = 0; v < 4; v++) {
        float4 a2v = *(const float4*)(a2p + 4 * v);
        A2[4*v] = a2v.x; A2[4*v+1] = a2v.y; A2[4*v+2] = a2v.z; A2[4*v+3] = a2v.w;
    }
#pragma unroll
    for (int s = 0; s < 16; s++) h[s] = 0.f;

    int l0 = dir ? (L_SEQ - 1 - chunk * CHUNK) : chunk * CHUNK;
    int stp = dir ? -1 : 1;
    float sumdel = 0.f;

#pragma unroll
    for (int i = 0; i < CHUNK; i++) {
        int l = l0 + i * stp;
        size_t p = (size_t)b * L_SEQ + l;
        const float* row = DBL + p * LDBL;
        float dtv = bdtv;
#pragma unroll
        for (int r = 0; r < 6; r++) dtv += row[r] * wd[r];
        float del = softplus_f(dtv);
        float xs  = b2f(XS[p * DI + d]);
        const float4* bm = (const float4*)(row + 8);
        float4 B0 = bm[0], B1 = bm[1], B2 = bm[2], B3 = bm[3];
        float Bm[16] = {B0.x,B0.y,B0.z,B0.w, B1.x,B1.y,B1.z,B1.w,
                        B2.x,B2.y,B2.z,B2.w, B3.x,B3.y,B3.z,B3.w};
        float dx = del * xs;
        sumdel += del;
#pragma unroll
        for (int s = 0; s < 16; s++) {
            float dA = exp2f(del * A2[s]);
            h[s] = dA * h[s] + dx * Bm[s];
        }
    }
    size_t idx = ((size_t)g * DI + d) * 16;
    f16x8 q0, q1, p0, p1;
#pragma unroll
    for (int j = 0; j < 8; j++) {
        q0[j] = (f16)h[j];
        q1[j] = (f16)h[8 + j];
        p0[j] = (f16)exp2f(A2[j] * sumdel);
        p1[j] = (f16)exp2f(A2[8 + j] * sumdel);
    }
    *(f16x8*)(Q + idx)     = q0;
    *(f16x8*)(Q + idx + 8) = q1;
    *(f16x8*)(P + idx)     = p0;
    *(f16x8*)(P + idx + 8) = p1;
}

// p2a: compose GRP consecutive chunk ops into one group op (f32).
__global__ void k_scan_p2a(const f16* __restrict__ P, const f16* __restrict__ Q,
                           float* __restrict__ Pg, float* __restrict__ Qg) {
    int t = blockIdx.x * blockDim.x + threadIdx.x;
    int s8 = t & 1;
    int d = (t >> 1) % DI;
    int rest = t / (DI * 2);
    int grp = rest % NGRP;
    int dirb = rest / NGRP;

    float Pr[8], Qr[8];
#pragma unroll
    for (int j = 0; j < 8; j++) { Pr[j] = 1.f; Qr[j] = 0.f; }

    size_t base = (((size_t)(dirb * NCH + grp * GRP)) * DI + d) * 16 + s8 * 8;
#pragma unroll 4
    for (int i = 0; i < GRP; i++) {
        size_t idx = base + (size_t)i * (DI * 16);
        f16x8 p8 = *(const f16x8*)(P + idx);
        f16x8 q8 = *(const f16x8*)(Q + idx);
#pragma unroll
        for (int j = 0; j < 8; j++) {
            float pv = (float)p8[j], qv = (float)q8[j];
            Qr[j] = pv * Qr[j] + qv;
            Pr[j] *= pv;
        }
    }
    size_t gidx = (((size_t)(dirb * NGRP + grp)) * DI + d) * 16 + s8 * 8;
#pragma unroll
    for (int v = 0; v < 2; v++) {
        *(float4*)(Pg + gidx + 4 * v) = make_float4(Pr[4*v], Pr[4*v+1], Pr[4*v+2], Pr[4*v+3]);
        *(float4*)(Qg + gidx + 4 * v) = make_float4(Qr[4*v], Qr[4*v+1], Qr[4*v+2], Qr[4*v+3]);
    }
}

// p2b: exclusive scan over NGRP group ops per (dirb,d,s).
__global__ void k_scan_p2b(const float* __restrict__ Pg, float* __restrict__ Qg) {
    int u = blockIdx.x * blockDim.x + threadIdx.x;   // 12288
    int s = u & 15;
    int dd = (u >> 4) % DI;
    int dirb = u / (DI * 16);
    float runQ = 0.f;
#pragma unroll
    for (int g = 0; g < NGRP; g++) {
        size_t i = (((size_t)(dirb * NGRP + g)) * DI + dd) * 16 + s;
        float pg = Pg[i], qg = Qg[i];
        Qg[i] = runQ;
        runQ = pg * runQ + qg;
    }
}

// p2c: replay GRP chunks from the group's exclusive prefix.
__global__ void k_scan_p2c(const f16* __restrict__ P, f16* __restrict__ Q,
                           const float* __restrict__ Qg) {
    int t = blockIdx.x * blockDim.x + threadIdx.x;
    int s8 = t & 1;
    int d = (t >> 1) % DI;
    int rest = t / (DI * 2);
    int grp = rest % NGRP;
    int dirb = rest / NGRP;

    size_t gidx = (((size_t)(dirb * NGRP + grp)) * DI + d) * 16 + s8 * 8;
    float runQ[8];
#pragma unroll
    for (int v = 0; v < 2; v++) {
        float4 qv = *(const float4*)(Qg + gidx + 4 * v);
        runQ[4*v] = qv.x; runQ[4*v+1] = qv.y; runQ[4*v+2] = qv.z; runQ[4*v+3] = qv.w;
    }

    size_t base = (((size_t)(dirb * NCH + grp * GRP)) * DI + d) * 16 + s8 * 8;
#pragma unroll 4
    for (int i = 0; i < GRP; i++) {
        size_t idx = base + (size_t)i * (DI * 16);
        f16x8 p8 = *(const f16x8*)(P + idx);
        f16x8 q8 = *(const f16x8*)(Q + idx);
        f16x8 o8;
#pragma unroll
        for (int j = 0; j < 8; j++) {
            o8[j] = (f16)runQ[j];
            runQ[j] = (float)p8[j] * runQ[j] + (float)q8[j];
        }
        *(f16x8*)(Q + idx) = o8;
    }
}

__global__ void k_scan_p3(const float* __restrict__ DBLF, const float* __restrict__ DBLB,
                          const bf16* __restrict__ XSF,  const bf16* __restrict__ XSB,
                          const bf16* __restrict__ XZF,  const bf16* __restrict__ XZB,
                          const float* __restrict__ fWdt, const float* __restrict__ fbdt,
                          const float* __restrict__ bWdt, const float* __restrict__ bbdt,
                          const float* __restrict__ a2tab,
                          const float* __restrict__ fD,    const float* __restrict__ bD,
                          const f16* __restrict__ Q,
                          bf16* __restrict__ YSF, bf16* __restrict__ YSB) {
    int t = blockIdx.x * blockDim.x + threadIdx.x;   // 393216
    int d = t % DI;
    int g = t / DI;
    int chunk = g & (NCH - 1);
    int dirb = g >> 9;
    int b = dirb & 1, dir = dirb >> 1;

    const float* DBL = dir ? DBLB : DBLF;
    const bf16*  XS  = dir ? XSB  : XSF;
    const bf16*  XZ  = dir ? XZB  : XZF;
    const float* wdt = (dir ? bWdt : fWdt) + d * 6;
    float bdtv = (dir ? bbdt : fbdt)[d];
    float Dp = dir ? bD[d] : fD[d];
    bf16* Y = dir ? YSB : YSF;

    float wd[6];
#pragma unroll
    for (int r = 0; r < 6; r++) wd[r] = wdt[r];
    const float* a2p = a2tab + (dir * DI + d) * 16;
    float A2[16], h[16];
#pragma unroll
    for (int v = 0; v < 4; v++) {
        float4 a2v = *(const float4*)(a2p + 4 * v);
        A2[4*v] = a2v.x; A2[4*v+1] = a2v.y; A2[4*v+2] = a2v.z; A2[4*v+3] = a2v.w;
    }
    size_t idx = ((size_t)g * DI + d) * 16;
    f16x8 q0 = *(const f16x8*)(Q + idx);
    f16x8 q1 = *(const f16x8*)(Q + idx + 8);
#pragma unroll
    for (int j = 0; j < 8; j++) { h[j] = (float)q0[j]; h[8 + j] = (float)q1[j]; }

    int l0 = dir ? (L_SEQ - 1 - chunk * CHUNK) : chunk * CHUNK;
    int stp = dir ? -1 : 1;

#pragma unroll
    for (int i = 0; i < CHUNK; i++) {
        int l = l0 + i * stp;
        size_t p = (size_t)b * L_SEQ + l;
        const float* row = DBL + p * LDBL;
        float dtv = bdtv;
#pragma unroll
        for (int r = 0; r < 6; r++) dtv += row[r] * wd[r];
        float del = softplus_f(dtv);
        float xs  = b2f(XS[p * DI + d]);
        float z   = b2f(XZ[p * 384 + 192 + d]);
        const float4* bm = (const float4*)(row + 8);
        float4 B0 = bm[0], B1 = bm[1], B2 = bm[2], B3 = bm[3];
        float4 C0 = bm[4], C1 = bm[5], C2 = bm[6], C3 = bm[7];
        float Bm[16] = {B0.x,B0.y,B0.z,B0.w, B1.x,B1.y,B1.z,B1.w,
                        B2.x,B2.y,B2.z,B2.w, B3.x,B3.y,B3.z,B3.w};
        float Cm[16] = {C0.x,C0.y,C0.z,C0.w, C1.x,C1.y,C1.z,C1.w,
                        C2.x,C2.y,C2.z,C2.w, C3.x,C3.y,C3.z,C3.w};
        float dx = del * xs;
        float pr = 0.f;
#pragma unroll
        for (int s = 0; s < 16; s++) {
            float dA = exp2f(del * A2[s]);
            h[s] = dA * h[s] + dx * Bm[s];
            pr += h[s] * Cm[s];
        }
        Y[p * DI + d] = __float2bfloat16((pr + xs * Dp) * silu_f(z));
    }
}

// ---------------------------------------------------------------------------
// K9: LDS-tiled mid with inline LN1 recompute.
// ---------------------------------------------------------------------------
__global__ void k_mid_t(const float* __restrict__ x, const float* __restrict__ YO,
                        const float* __restrict__ gamma1,
                        const float* __restrict__ ln1w, const float* __restrict__ ln1b,
                        float* __restrict__ XMID, bf16* __restrict__ XM2cl) {
    __shared__ float xt[DIM][TP + 1];
    __shared__ float yt[DIM][TP + 1];
    __shared__ float rs[8][TP], rss[8][TP];
    __shared__ float uu[TP], rr[TP];
    int p0 = blockIdx.x * TP;
    int b = p0 >> 12, l0 = p0 & (L_SEQ - 1);
    int t = threadIdx.x;
    int tg = t >> 5, li = t & 31;

    for (int idx = t; idx < DIM * TP; idx += 256) {
        int c = idx >> 5, q = idx & 31;
        xt[c][q] = x[((size_t)(b * DIM + c)) * L_SEQ + l0 + q];
    }
    for (int idx = t; idx < DIM * TP; idx += 256) {
        int q = idx / DIM, c = idx % DIM;
        yt[c][q] = YO[(size_t)(p0 + q) * DIM + c];
    }
    __syncthreads();
    {
        float s = 0.f, ss = 0.f;
        for (int c = tg; c < DIM; c += 8) { float v = xt[c][li]; s += v; ss += v * v; }
        rs[tg][li] = s; rss[tg][li] = ss;
    }
    __syncthreads();
    if (t < TP) {
        float s = 0.f, ss = 0.f;
#pragma unroll
        for (int g = 0; g < 8; g++) { s += rs[g][t]; ss += rss[g][t]; }
        float u = s / DIM;
        uu[t] = u; rr[t] = rsqrtf(ss / DIM - u * u + 1e-6f);
    }
    __syncthreads();
    {
        float u = uu[li], r = rr[li];
        float s = 0.f, ss = 0.f;
        for (int c = tg; c < DIM; c += 8) {
            float xv = xt[c][li];
            float x1 = ln1w[c] * (xv - u) * r + ln1b[c];
            float v = xv + gamma1[c] * (yt[c][li] + x1);
            XMID[((size_t)(b * DIM + c)) * L_SEQ + l0 + li] = v;
            xt[c][li] = v;
            s += v; ss += v * v;
        }
        rs[tg][li] = s; rss[tg][li] = ss;
    }
    __syncthreads();
    if (t < TP) {
        float s = 0.f, ss = 0.f;
#pragma unroll
        for (int g = 0; g < 8; g++) { s += rs[g][t]; ss += rss[g][t]; }
        float u = s / DIM;
        uu[t] = u; rr[t] = rsqrtf(ss / DIM - u * u + 1e-6f);
    }
    __syncthreads();
    for (int idx = t; idx < DIM * TP; idx += 256) {
        int q = idx / DIM, c = idx % DIM;
        XM2cl[(size_t)(p0 + q) * DIM + c] =
            __float2bfloat16(ln1w[c] * (xt[c][q] - uu[q]) * rr[q] + ln1b[c]);
    }
}

// ---------------------------------------------------------------------------
// K11: fused dilated dwconvs + GELU gate, vectorized 8 channels/thread.
// ---------------------------------------------------------------------------
__global__ void k_msff_v(const bf16* __restrict__ H, const float* __restrict__ mdwt,
                         bf16* __restrict__ G) {
    int i = blockIdx.x * blockDim.x + threadIdx.x;   // NPOS*24
    int cg = i % 24;
    int p = i / 24;
    int c0 = cg * 8;
    int b = p >> 12, l = p & (L_SEQ - 1);
    int y = l >> 6, xc = l & 63;
    float a1[8] = {}, a2[8] = {}, a3[8] = {};
    const unsigned short* Hu = (const unsigned short*)H;

#pragma unroll
    for (int ky = 0; ky < 3; ky++) {
#pragma unroll
        for (int kx = 0; kx < 3; kx++) {
            int tap = ky * 3 + kx;
            {
                int y1 = y + (ky - 1), x1 = xc + (kx - 1);
                if (y1 >= 0 && y1 < 64 && x1 >= 0 && x1 < 64) {
                    float4 w0 = *(const float4*)(mdwt + tap * 192 + c0);
                    float4 w1 = *(const float4*)(mdwt + tap * 192 + c0 + 4);
                    ushort8 hv = *(const ushort8*)(Hu +
                        ((size_t)(b * L_SEQ + y1 * 64 + x1)) * 576 + c0);
                    float wv[8] = {w0.x,w0.y,w0.z,w0.w, w1.x,w1.y,w1.z,w1.w};
#pragma unroll
                    for (int j = 0; j < 8; j++) a1[j] += wv[j] * us2f(hv[j]);
                }
            }
            {
                int y2 = y + (ky - 1) * 2, x2 = xc + (kx - 1) * 2;
                if (y2 >= 0 && y2 < 64 && x2 >= 0 && x2 < 64) {
                    float4 w0 = *(const float4*)(mdwt + (9 + tap) * 192 + c0);
                    float4 w1 = *(const float4*)(mdwt + (9 + tap) * 192 + c0 + 4);
                    ushort8 hv = *(const ushort8*)(Hu +
                        ((size_t)(b * L_SEQ + y2 * 64 + x2)) * 576 + 192 + c0);
                    float wv[8] = {w0.x,w0.y,w0.z,w0.w, w1.x,w1.y,w1.z,w1.w};
#pragma unroll
                    for (int j = 0; j < 8; j++) a2[j] += wv[j] * us2f(hv[j]);
                }
            }
            {
                int y3 = y + (ky - 1) * 3, x3 = xc + (kx - 1) * 3;
                if (y3 >= 0 && y3 < 64 && x3 >= 0 && x3 < 64) {
                    float4 w0 = *(const float4*)(mdwt + (18 + tap) * 192 + c0);
                    float4 w1 = *(const float4*)(mdwt + (18 + tap) * 192 + c0 + 4);
                    ushort8 hv = *(const ushort8*)(Hu +
                        ((size_t)(b * L_SEQ + y3 * 64 + x3)) * 576 + 384 + c0);
                    float wv[8] = {w0.x,w0.y,w0.z,w0.w, w1.x,w1.y,w1.z,w1.w};
#pragma unroll
                    for (int j = 0; j < 8; j++) a3[j] += wv[j] * us2f(hv[j]);
                }
            }
        }
    }
    ushort8 ov;
#pragma unroll
    for (int j = 0; j < 8; j++) {
        float ge = 0.5f * a1[j] * (1.f + erff(a1[j] * 0.70710678118f));
        bf16 t = __float2bfloat16(ge * a2[j] * a3[j]);
        ov[j] = *(unsigned short*)&t;
    }
    *(ushort8*)((unsigned short*)G + (size_t)p * HID + c0) = ov;
}

// ---------------------------------------------------------------------------
extern "C" void kernel_launch(void* const* d_in, const int* in_sizes, int n_in,
                              void* d_out, int out_size, void* d_ws, size_t ws_size,
                              hipStream_t stream) {
    const float* x      = (const float*)d_in[0];
    const float* gamma1 = (const float*)d_in[1];
    const float* gamma2 = (const float*)d_in[2];
    const float* ln1w   = (const float*)d_in[3];
    const float* ln1b   = (const float*)d_in[4];
    const float* mnw    = (const float*)d_in[5];
    const float* mnb    = (const float*)d_in[6];
    const float* fWin   = (const float*)d_in[7];
    const float* fconvw = (const float*)d_in[8];
    const float* fconvb = (const float*)d_in[9];
    const float* fWx    = (const float*)d_in[10];
    const float* fWdt   = (const float*)d_in[11];
    const float* fbdt   = (const float*)d_in[12];
    const float* fAlog  = (const float*)d_in[13];
    const float* fD     = (const float*)d_in[14];
    const float* bWin   = (const float*)d_in[15];
    const float* bconvw = (const float*)d_in[16];
    const float* bconvb = (const float*)d_in[17];
    const float* bWx    = (const float*)d_in[18];
    const float* bWdt   = (const float*)d_in[19];
    const float* bbdt   = (const float*)d_in[20];
    const float* bAlog  = (const float*)d_in[21];
    const float* bD     = (const float*)d_in[22];
    const float* Wout   = (const float*)d_in[23];
    const float* mwin   = (const float*)d_in[24];
    const float* mdw1   = (const float*)d_in[25];
    const float* mdw2   = (const float*)d_in[26];
    const float* mdw3   = (const float*)d_in[27];
    const float* mwout  = (const float*)d_in[28];
    float* out = (float*)d_out;

    float* ws = (float*)d_ws;
    // Fully dedicated regions (no overlays). float offsets; total ~77 MB.
    bf16*  XNbf  = (bf16*)(ws);              // 786432 bf16 (393216 f)
    bf16*  XZF   = (bf16*)(ws + 393216);     // 3145728 bf16 (1572864 f)
    bf16*  XZB   = (bf16*)(ws + 1966080);    // 3145728 bf16
    bf16*  XSF   = (bf16*)(ws + 3538944);    // 1572864 bf16 (786432 f)
    bf16*  XSB   = (bf16*)(ws + 4325376);    // 1572864 bf16
    float* DBLF  = ws + 5111808;             // 327680
    float* DBLB  = ws + 5439488;             // 327680
    f16*   Ph    = (f16*)(ws + 5767168);     // 6291456 f16 (3145728 f)
    f16*   Qh    = (f16*)(ws + 8912896);     // 6291456 f16
    bf16*  YSFbf = (bf16*)(ws + 12058624);   // 1572864 bf16
    bf16*  YSBbf = (bf16*)(ws + 12845056);   // 1572864 bf16
    float* YO    = ws + 13631488;            // 786432
    float* XMID  = ws + 14417920;            // 786432
    bf16*  XM2cl = (bf16*)(ws + 15204352);   // 786432 bf16 (393216 f)
    bf16*  Hcl   = (bf16*)(ws + 15597568);   // 4718592 bf16 (2359296 f)
    bf16*  Gcl   = (bf16*)(ws + 17956864);   // 1572864 bf16 (786432 f)
    bf16*  WAR   = (bf16*)(ws + 18743296);   // 180480 bf16 (90240 f)
    float* A2tab = ws + 18833536;            // 6144
    float* MDWT  = ws + 18839680;            // 5184
    float* Pgb   = ws + 18844864;            // 196608
    float* Qgb   = ws + 19041472;            // 196608 -> end 19238080 (~77 MB)

    const bf16* fWinB  = WAR;
    const bf16* bWinB  = WAR + 36864;
    const bf16* fWxB   = WAR + 73728;
    const bf16* bWxB   = WAR + 81024;
    const bf16* WoutB  = WAR + 88320;
    const bf16* mwinB  = WAR + 106752;
    const bf16* mwoutB = WAR + 162048;

    // 1. fused double-LN + prep (blocks 0..255 LN, 256..1005 prep)
    k_ln12_prep<<<NPOS / TP + 750, 256, 0, stream>>>(x, ln1w, ln1b, mnw, mnb, XNbf,
                                                     fWin, bWin, fWx, bWx, Wout, mwin, mwout,
                                                     fAlog, bAlog, mdw1, mdw2, mdw3,
                                                     WAR, A2tab, MDWT);
    // 2. in-projections, both dirs
    mfma_nt_dir<<<dim3(128, 6, 2), 256, 0, stream>>>(XNbf, XNbf, fWinB, bWinB,
                                                     XZF, XZB, NPOS, 384, DIM, 384, 0, 1);
    // 3. dwconv + silu (vectorized, both dirs)
    k_conv_v<<<dim3(NPOS * 24 / 256, 2), 256, 0, stream>>>(XZF, XZB, fconvw, fconvb,
                                                           bconvw, bconvb, XSF, XSB);
    // 4. x_dbl projections, both dirs (padded LDBL rows)
    mfma_nt_dir<<<dim3(128, 1, 2), 256, 0, stream>>>(XSF, XSB, fWxB, bWxB,
                                                     DBLF, DBLB, NPOS, 38, DI, LDBL, 1, 0);
    // 5-9. chunked parallel scan (CHUNK=8, unrolled) with hierarchical p2
    k_scan_p1<<<NREC * NCH / 256, 256, 0, stream>>>(DBLF, DBLB, XSF, XSB,
                                                    fWdt, fbdt, bWdt, bbdt,
                                                    A2tab, Ph, Qh);
    k_scan_p2a<<<4 * NGRP * DI * 2 / 256, 256, 0, stream>>>(Ph, Qh, Pgb, Qgb);
    k_scan_p2b<<<NREC * 16 / 256, 256, 0, stream>>>(Pgb, Qgb);
    k_scan_p2c<<<4 * NGRP * DI * 2 / 256, 256, 0, stream>>>(Ph, Qh, Qgb);
    k_scan_p3<<<NREC * NCH / 256, 256, 0, stream>>>(DBLF, DBLB, XSF, XSB, XZF, XZB,
                                                    fWdt, fbdt, bWdt, bbdt,
                                                    A2tab, fD, bD, Qh,
                                                    YSFbf, YSBbf);
    // 10. out-projection (dual-A MFMA, f32 channel-last YO)
    mfma_out<<<dim3(128, 2), 256, 0, stream>>>(YSFbf, YSBbf, WoutB, YO, NPOS, DIM, DI, DIM);
    // 11. residual + LN (LDS-tiled, LN1 recomputed inline)
    k_mid_t<<<NPOS / TP, 256, 0, stream>>>(x, YO, gamma1, ln1w, ln1b, XMID, XM2cl);
    // 12. msff in-projection (MFMA, bf16 channel-last H)
    mfma_nt<<<dim3(128, 9), 256, 0, stream>>>(XM2cl, mwinB, Hcl, NPOS, 576, DIM, 576);
    // 13. fused dilated dwconvs + GELU gate (vectorized)
    k_msff_v<<<NPOS * 24 / 256, 256, 0, stream>>>(Hcl, MDWT, Gcl);
    // 14. msff out-projection + fused final residual -> out
    mfma_msffout<<<dim3(2, 128), 256, 0, stream>>>(mwoutB, Gcl, XMID, gamma2, out, DIM, HID);
}

// Round 15
// 290.659 us; speedup vs baseline: 1.0125x; 1.0125x over previous
//
#include <hip/hip_runtime.h>
#include <hip/hip_bf16.h>
#include <math.h>

typedef __hip_bfloat16 bf16;
typedef _Float16 f16;
typedef f16  f16x8  __attribute__((ext_vector_type(8)));
typedef short short8 __attribute__((ext_vector_type(8)));
typedef unsigned short ushort8 __attribute__((ext_vector_type(8)));
typedef float floatx4 __attribute__((ext_vector_type(4)));

#define L_SEQ 4096
#define BATCH 2
#define DIM   96
#define DI    192
#define DS    16
#define HID   192
#define NPOS  (BATCH * L_SEQ)   // 8192
#define NCH   512               // chunks per sequence
#define CHUNK 8                 // L_SEQ / NCH
#define GRP   32                // chunks per p2 group
#define NGRP  (NCH / GRP)       // 16 groups
#define NREC  (2 * BATCH * DI)  // 768 recurrences (dir,b,d)
#define LDBL  40                // padded x_dbl row stride: dt[0:6), B[8:24), C[24:40)
#define LOG2E 1.44269504088896f
#define TP    32                // positions per LN block

__device__ __forceinline__ float silu_f(float x) { return x / (1.f + __expf(-x)); }
__device__ __forceinline__ float softplus_f(float x) {
    return fmaxf(x, 0.f) + __logf(1.f + __expf(-fabsf(x)));
}
__device__ __forceinline__ float b2f(bf16 v) { return __bfloat162float(v); }
__device__ __forceinline__ float us2f(unsigned short u) {
    union { unsigned int i; float f; } cv; cv.i = ((unsigned int)u) << 16; return cv.f;
}

// ---------------------------------------------------------------------------
// K0: prep — cast GEMM weights fp32->bf16, build A2 table, transpose msff dw.
// ---------------------------------------------------------------------------
__global__ void k_prep(const float* __restrict__ fWin, const float* __restrict__ bWin,
                       const float* __restrict__ fWx,  const float* __restrict__ bWx,
                       const float* __restrict__ Wout, const float* __restrict__ mwin,
                       const float* __restrict__ mwout,
                       const float* __restrict__ fAlog, const float* __restrict__ bAlog,
                       const float* __restrict__ mdw1, const float* __restrict__ mdw2,
                       const float* __restrict__ mdw3,
                       bf16* __restrict__ war, float* __restrict__ a2tab,
                       float* __restrict__ mdwt) {
    int i = blockIdx.x * blockDim.x + threadIdx.x;
    if (i < 180480) {
        float v;
        if (i < 36864)        v = fWin[i];
        else if (i < 73728)   v = bWin[i - 36864];
        else if (i < 81024)   v = fWx[i - 73728];
        else if (i < 88320)   v = bWx[i - 81024];
        else if (i < 106752)  v = Wout[i - 88320];
        else if (i < 162048)  v = mwin[i - 106752];
        else                  v = mwout[i - 162048];
        war[i] = __float2bfloat16(v);
    } else if (i < 186624) {
        int j = i - 180480;                 // 0..6143
        int dir = j / 3072, rem = j % 3072; // [dir][d][s]
        const float* al = dir ? bAlog : fAlog;
        a2tab[j] = -__expf(al[rem]) * LOG2E;
    } else if (i < 191808) {
        int j = i - 186624;                 // 0..5183
        int cv = j / 1728, rem = j % 1728;
        int tap = rem / 192, c = rem % 192;
        const float* src = (cv == 0) ? mdw1 : (cv == 1) ? mdw2 : mdw3;
        mdwt[j] = src[c * 9 + tap];
    }
}

// ---------------------------------------------------------------------------
// K1: LDS-tiled double layernorm. No X1 store (k_mid recomputes LN1 inline).
// ---------------------------------------------------------------------------
__global__ void k_ln12_t(const float* __restrict__ x,
                         const float* __restrict__ ln1w, const float* __restrict__ ln1b,
                         const float* __restrict__ mnw,  const float* __restrict__ mnb,
                         bf16* __restrict__ XNbf) {
    __shared__ float xt[DIM][TP + 1];
    __shared__ float rs[8][TP], rss[8][TP];
    __shared__ float uu[TP], rr[TP];
    int p0 = blockIdx.x * TP;
    int b = p0 >> 12, l0 = p0 & (L_SEQ - 1);
    int t = threadIdx.x;
    int tg = t >> 5, li = t & 31;

    for (int idx = t; idx < DIM * TP; idx += 256) {
        int c = idx >> 5, q = idx & 31;
        xt[c][q] = x[((size_t)(b * DIM + c)) * L_SEQ + l0 + q];
    }
    __syncthreads();
    {
        float s = 0.f, ss = 0.f;
        for (int c = tg; c < DIM; c += 8) { float v = xt[c][li]; s += v; ss += v * v; }
        rs[tg][li] = s; rss[tg][li] = ss;
    }
    __syncthreads();
    if (t < TP) {
        float s = 0.f, ss = 0.f;
#pragma unroll
        for (int g = 0; g < 8; g++) { s += rs[g][t]; ss += rss[g][t]; }
        float u = s / DIM;
        uu[t] = u; rr[t] = rsqrtf(ss / DIM - u * u + 1e-6f);
    }
    __syncthreads();
    {
        float u = uu[li], r = rr[li];
        float s2 = 0.f, ss2 = 0.f;
        for (int c = tg; c < DIM; c += 8) {
            float tv = ln1w[c] * (xt[c][li] - u) * r + ln1b[c];
            xt[c][li] = tv;
            s2 += tv; ss2 += tv * tv;
        }
        rs[tg][li] = s2; rss[tg][li] = ss2;
    }
    __syncthreads();
    if (t < TP) {
        float s = 0.f, ss = 0.f;
#pragma unroll
        for (int g = 0; g < 8; g++) { s += rs[g][t]; ss += rss[g][t]; }
        float u = s / DIM;
        uu[t] = u; rr[t] = rsqrtf(ss / DIM - u * u + 1e-5f);
    }
    __syncthreads();
    for (int idx = t; idx < DIM * TP; idx += 256) {
        int q = idx / DIM, c = idx % DIM;
        XNbf[(size_t)(p0 + q) * DIM + c] =
            __float2bfloat16((xt[c][q] - uu[q]) * rr[q] * mnw[c] + mnb[c]);
    }
}

// ---------------------------------------------------------------------------
// MFMA NT GEMM, 2-dir batched via blockIdx.z.
// ---------------------------------------------------------------------------
__global__ void mfma_nt_dir(const bf16* __restrict__ A0, const bf16* __restrict__ A1,
                            const bf16* __restrict__ W0, const bf16* __restrict__ W1,
                            void* __restrict__ C0, void* __restrict__ C1,
                            int M, int N, int K, int ldc, int pad6, int obf) {
    int z = blockIdx.z;
    const bf16* A = z ? A1 : A0;
    const bf16* W = z ? W1 : W0;
    void* C = z ? C1 : C0;
    int wave = threadIdx.x >> 6, lane = threadIdx.x & 63;
    int m0 = blockIdx.x * 64 + wave * 16;
    int n0 = blockIdx.y * 64;
    int lm = lane & 15, quad = lane >> 4;
    const short* Ap = (const short*)A + (size_t)(m0 + lm) * K + quad * 8;
    const short* Wp = (const short*)W;
    floatx4 acc[4];
#pragma unroll
    for (int t = 0; t < 4; t++) acc[t] = (floatx4){0.f, 0.f, 0.f, 0.f};
    for (int k0 = 0; k0 < K; k0 += 32) {
        short8 a = *(const short8*)(Ap + k0);
#pragma unroll
        for (int t = 0; t < 4; t++) {
            int n = n0 + t * 16 + lm;
            short8 b = (n < N) ? *(const short8*)(Wp + (size_t)n * K + k0 + quad * 8)
                               : (short8){0,0,0,0,0,0,0,0};
            acc[t] = __builtin_amdgcn_mfma_f32_16x16x32_bf16(a, b, acc[t], 0, 0, 0);
        }
    }
#pragma unroll
    for (int t = 0; t < 4; t++) {
        int n = n0 + t * 16 + lm;
        if (n < N) {
            int nn = (pad6 && n >= 6) ? n + 2 : n;
#pragma unroll
            for (int r = 0; r < 4; r++) {
                int m = m0 + quad * 4 + r;
                if (obf) ((bf16*)C)[(size_t)m * ldc + nn] = __float2bfloat16(acc[t][r]);
                else     ((float*)C)[(size_t)m * ldc + nn] = acc[t][r];
            }
        }
    }
}

// ---------------------------------------------------------------------------
// MFMA NT single-matrix (msff in-projection): C = A @ W^T, bf16 out.
// ---------------------------------------------------------------------------
__global__ void mfma_nt(const bf16* __restrict__ A, const bf16* __restrict__ W,
                        bf16* __restrict__ C, int M, int N, int K, int ldc) {
    int wave = threadIdx.x >> 6, lane = threadIdx.x & 63;
    int m0 = blockIdx.x * 64 + wave * 16;
    int n0 = blockIdx.y * 64;
    int lm = lane & 15, quad = lane >> 4;
    const short* Ap = (const short*)A + (size_t)(m0 + lm) * K + quad * 8;
    const short* Wp = (const short*)W;
    floatx4 acc[4];
#pragma unroll
    for (int t = 0; t < 4; t++) acc[t] = (floatx4){0.f, 0.f, 0.f, 0.f};
    for (int k0 = 0; k0 < K; k0 += 32) {
        short8 a = *(const short8*)(Ap + k0);
#pragma unroll
        for (int t = 0; t < 4; t++) {
            int n = n0 + t * 16 + lm;
            short8 b = (n < N) ? *(const short8*)(Wp + (size_t)n * K + k0 + quad * 8)
                               : (short8){0,0,0,0,0,0,0,0};
            acc[t] = __builtin_amdgcn_mfma_f32_16x16x32_bf16(a, b, acc[t], 0, 0, 0);
        }
    }
#pragma unroll
    for (int t = 0; t < 4; t++) {
        int n = n0 + t * 16 + lm;
        if (n < N) {
#pragma unroll
            for (int r = 0; r < 4; r++) {
                int m = m0 + quad * 4 + r;
                C[(size_t)m * ldc + n] = __float2bfloat16(acc[t][r]);
            }
        }
    }
}

// ---------------------------------------------------------------------------
// Out-projection, dual-A: YO = (Y1+Y2) @ Wout^T, f32 channel-last out.
// ---------------------------------------------------------------------------
__global__ void mfma_out(const bf16* __restrict__ Y1, const bf16* __restrict__ Y2,
                         const bf16* __restrict__ W, float* __restrict__ C,
                         int M, int N, int K, int ldc) {
    int wave = threadIdx.x >> 6, lane = threadIdx.x & 63;
    int m0 = blockIdx.x * 64 + wave * 16;
    int n0 = blockIdx.y * 64;
    int lm = lane & 15, quad = lane >> 4;
    const short* A1p = (const short*)Y1 + (size_t)(m0 + lm) * K + quad * 8;
    const short* A2p = (const short*)Y2 + (size_t)(m0 + lm) * K + quad * 8;
    const short* Wp  = (const short*)W;
    floatx4 acc[4];
#pragma unroll
    for (int t = 0; t < 4; t++) acc[t] = (floatx4){0.f, 0.f, 0.f, 0.f};
    for (int k0 = 0; k0 < K; k0 += 32) {
        short8 a1 = *(const short8*)(A1p + k0);
        short8 a2 = *(const short8*)(A2p + k0);
#pragma unroll
        for (int t = 0; t < 4; t++) {
            int n = n0 + t * 16 + lm;
            short8 b = (n < N) ? *(const short8*)(Wp + (size_t)n * K + k0 + quad * 8)
                               : (short8){0,0,0,0,0,0,0,0};
            acc[t] = __builtin_amdgcn_mfma_f32_16x16x32_bf16(a1, b, acc[t], 0, 0, 0);
            acc[t] = __builtin_amdgcn_mfma_f32_16x16x32_bf16(a2, b, acc[t], 0, 0, 0);
        }
    }
#pragma unroll
    for (int t = 0; t < 4; t++) {
        int n = n0 + t * 16 + lm;
        if (n < N) {
#pragma unroll
            for (int r = 0; r < 4; r++) {
                int m = m0 + quad * 4 + r;
                C[(size_t)m * ldc + n] = acc[t][r];
            }
        }
    }
}

// ---------------------------------------------------------------------------
// msff out-projection + fused final residual (planar f32 out).
// ---------------------------------------------------------------------------
__global__ void mfma_msffout(const bf16* __restrict__ A, const bf16* __restrict__ Bm,
                             const float* __restrict__ XMID, const float* __restrict__ gamma2,
                             float* __restrict__ out, int M, int K) {
    int wave = threadIdx.x >> 6, lane = threadIdx.x & 63;
    int m0 = blockIdx.x * 64 + wave * 16;
    int n0 = blockIdx.y * 64;
    int lm = lane & 15, quad = lane >> 4;
    int am = m0 + lm;
    bool aval = am < M;
    const short* Ap = (const short*)A + (size_t)am * K + quad * 8;
    const short* Bp = (const short*)Bm;
    floatx4 acc[4];
#pragma unroll
    for (int t = 0; t < 4; t++) acc[t] = (floatx4){0.f, 0.f, 0.f, 0.f};
    for (int k0 = 0; k0 < K; k0 += 32) {
        short8 a = aval ? *(const short8*)(Ap + k0) : (short8){0,0,0,0,0,0,0,0};
#pragma unroll
        for (int t = 0; t < 4; t++) {
            int n = n0 + t * 16 + lm;
            short8 b = *(const short8*)(Bp + (size_t)n * K + k0 + quad * 8);
            acc[t] = __builtin_amdgcn_mfma_f32_16x16x32_bf16(a, b, acc[t], 0, 0, 0);
        }
    }
#pragma unroll
    for (int t = 0; t < 4; t++) {
        int n = n0 + t * 16 + lm;
        int b = n >> 12, l = n & (L_SEQ - 1);
#pragma unroll
        for (int r = 0; r < 4; r++) {
            int m = m0 + quad * 4 + r;
            if (m < M) {
                size_t idx = ((size_t)(b * M + m)) * L_SEQ + l;
                out[idx] = XMID[idx] + gamma2[m] * acc[t][r];
            }
        }
    }
}

// ---------------------------------------------------------------------------
// K3: dwconv1d k=4 + bias + silu, vectorized 8 channels/thread.
// ---------------------------------------------------------------------------
__global__ void k_conv_v(const bf16* __restrict__ XZF, const bf16* __restrict__ XZB,
                         const float* __restrict__ fw, const float* __restrict__ fb,
                         const float* __restrict__ bw, const float* __restrict__ bb,
                         bf16* __restrict__ XSF, bf16* __restrict__ XSB) {
    int dirb = blockIdx.y;
    int i = blockIdx.x * blockDim.x + threadIdx.x;   // NPOS*24
    int dg = i % 24;
    int p = i / 24;
    int b = p >> 12, l = p & (L_SEQ - 1);
    int d0 = dg * 8;
    const bf16* XZ = dirb ? XZB : XZF;
    const float* cw = dirb ? bw : fw;
    const float* cb = dirb ? bb : fb;

    float4 w[8];
#pragma unroll
    for (int j = 0; j < 8; j++) w[j] = *(const float4*)(cw + (d0 + j) * 4);
    float acc[8];
#pragma unroll
    for (int j = 0; j < 8; j++) acc[j] = cb[d0 + j];

#pragma unroll
    for (int k = 0; k < 4; k++) {
        int ls = dirb ? (l + 3 - k) : (l - 3 + k);
        if (ls >= 0 && ls < L_SEQ) {
            ushort8 xv = *(const ushort8*)((const unsigned short*)XZ +
                           ((size_t)(b * L_SEQ + ls)) * 384 + d0);
#pragma unroll
            for (int j = 0; j < 8; j++) {
                float wk = (k == 0) ? w[j].x : (k == 1) ? w[j].y : (k == 2) ? w[j].z : w[j].w;
                acc[j] += wk * us2f(xv[j]);
            }
        }
    }
    ushort8 ov;
#pragma unroll
    for (int j = 0; j < 8; j++) {
        bf16 t = __float2bfloat16(silu_f(acc[j]));
        ov[j] = *(unsigned short*)&t;
    }
    *(ushort8*)((unsigned short*)(dirb ? XSB : XSF) + (size_t)p * DI + d0) = ov;
}

// ---------------------------------------------------------------------------
// Chunked parallel scan, CHUNK=8, NCH=512, A2 table-driven, P/Q fp16.
// Thread map p1/p3: t = g*DI + d, g = dirb*NCH + chunk.
// ---------------------------------------------------------------------------
__global__ void k_scan_p1(const float* __restrict__ DBLF, const float* __restrict__ DBLB,
                          const bf16* __restrict__ XSF,  const bf16* __restrict__ XSB,
                          const float* __restrict__ fWdt, const float* __restrict__ fbdt,
                          const float* __restrict__ bWdt, const float* __restrict__ bbdt,
                          const float* __restrict__ a2tab,
                          f16* __restrict__ P, f16* __restrict__ Q) {
    int t = blockIdx.x * blockDim.x + threadIdx.x;   // 393216
    int d = t % DI;
    int g = t / DI;                                   // 0..2047
    int chunk = g & (NCH - 1);
    int dirb = g >> 9;
    int b = dirb & 1, dir = dirb >> 1;

    const float* DBL = dir ? DBLB : DBLF;
    const bf16*  XS  = dir ? XSB  : XSF;
    const float* wdt = (dir ? bWdt : fWdt) + d * 6;
    float bdtv = (dir ? bbdt : fbdt)[d];

    float wd[6];
#pragma unroll
    for (int r = 0; r < 6; r++) wd[r] = wdt[r];
    const float* a2p = a2tab + (dir * DI + d) * 16;
    float A2[16], h[16];
#pragma unroll
    for (int v = 0; v < 4; v++) {
        float4 a2v = *(const float4*)(a2p + 4 * v);
        A2[4*v] = a2v.x; A2[4*v+1] = a2v.y; A2[4*v+2] = a2v.z; A2[4*v+3] = a2v.w;
    }
#pragma unroll
    for (int s = 0; s < 16; s++) h[s] = 0.f;

    int l = dir ? (L_SEQ - 1 - chunk * CHUNK) : chunk * CHUNK;
    int stp = dir ? -1 : 1;
    float sumdel = 0.f;

    for (int i = 0; i < CHUNK; i++) {
        size_t p = (size_t)b * L_SEQ + l;
        const float* row = DBL + p * LDBL;
        float dtv = bdtv;
#pragma unroll
        for (int r = 0; r < 6; r++) dtv += row[r] * wd[r];
        float del = softplus_f(dtv);
        float xs  = b2f(XS[p * DI + d]);
        const float4* bm = (const float4*)(row + 8);
        float4 B0 = bm[0], B1 = bm[1], B2 = bm[2], B3 = bm[3];
        float Bm[16] = {B0.x,B0.y,B0.z,B0.w, B1.x,B1.y,B1.z,B1.w,
                        B2.x,B2.y,B2.z,B2.w, B3.x,B3.y,B3.z,B3.w};
        float dx = del * xs;
        sumdel += del;
#pragma unroll
        for (int s = 0; s < 16; s++) {
            float dA = exp2f(del * A2[s]);
            h[s] = dA * h[s] + dx * Bm[s];
        }
        l += stp;
    }
    size_t idx = ((size_t)g * DI + d) * 16;
    f16x8 q0, q1, p0, p1;
#pragma unroll
    for (int j = 0; j < 8; j++) {
        q0[j] = (f16)h[j];
        q1[j] = (f16)h[8 + j];
        p0[j] = (f16)exp2f(A2[j] * sumdel);
        p1[j] = (f16)exp2f(A2[8 + j] * sumdel);
    }
    *(f16x8*)(Q + idx)     = q0;
    *(f16x8*)(Q + idx + 8) = q1;
    *(f16x8*)(P + idx)     = p0;
    *(f16x8*)(P + idx + 8) = p1;
}

// p2a: compose GRP consecutive chunk ops into one group op (f32).
// thread: t = ((dirb*NGRP + grp)*DI + d)*2 + s8   (24576 threads)
__global__ void k_scan_p2a(const f16* __restrict__ P, const f16* __restrict__ Q,
                           float* __restrict__ Pg, float* __restrict__ Qg) {
    int t = blockIdx.x * blockDim.x + threadIdx.x;
    int s8 = t & 1;
    int d = (t >> 1) % DI;
    int rest = t / (DI * 2);
    int grp = rest % NGRP;
    int dirb = rest / NGRP;

    float Pr[8], Qr[8];
#pragma unroll
    for (int j = 0; j < 8; j++) { Pr[j] = 1.f; Qr[j] = 0.f; }

    size_t base = (((size_t)(dirb * NCH + grp * GRP)) * DI + d) * 16 + s8 * 8;
    for (int i = 0; i < GRP; i++) {
        size_t idx = base + (size_t)i * (DI * 16);
        f16x8 p8 = *(const f16x8*)(P + idx);
        f16x8 q8 = *(const f16x8*)(Q + idx);
#pragma unroll
        for (int j = 0; j < 8; j++) {
            float pv = (float)p8[j], qv = (float)q8[j];
            Qr[j] = pv * Qr[j] + qv;
            Pr[j] *= pv;
        }
    }
    size_t gidx = (((size_t)(dirb * NGRP + grp)) * DI + d) * 16 + s8 * 8;
#pragma unroll
    for (int v = 0; v < 2; v++) {
        *(float4*)(Pg + gidx + 4 * v) = make_float4(Pr[4*v], Pr[4*v+1], Pr[4*v+2], Pr[4*v+3]);
        *(float4*)(Qg + gidx + 4 * v) = make_float4(Qr[4*v], Qr[4*v+1], Qr[4*v+2], Qr[4*v+3]);
    }
}

// p2b: exclusive scan over NGRP group ops per (dirb,d,s); Qg <- exclusive Q.
__global__ void k_scan_p2b(const float* __restrict__ Pg, float* __restrict__ Qg) {
    int u = blockIdx.x * blockDim.x + threadIdx.x;   // 12288
    int s = u & 15;
    int dd = (u >> 4) % DI;
    int dirb = u / (DI * 16);
    float runQ = 0.f;
#pragma unroll
    for (int g = 0; g < NGRP; g++) {
        size_t i = (((size_t)(dirb * NGRP + g)) * DI + dd) * 16 + s;
        float pg = Pg[i], qg = Qg[i];
        Qg[i] = runQ;
        runQ = pg * runQ + qg;
    }
}

// p2c: replay GRP chunks from the group's exclusive prefix; Q[chunk] <- state
// at chunk start (f16).
__global__ void k_scan_p2c(const f16* __restrict__ P, f16* __restrict__ Q,
                           const float* __restrict__ Qg) {
    int t = blockIdx.x * blockDim.x + threadIdx.x;
    int s8 = t & 1;
    int d = (t >> 1) % DI;
    int rest = t / (DI * 2);
    int grp = rest % NGRP;
    int dirb = rest / NGRP;

    size_t gidx = (((size_t)(dirb * NGRP + grp)) * DI + d) * 16 + s8 * 8;
    float runQ[8];
#pragma unroll
    for (int v = 0; v < 2; v++) {
        float4 qv = *(const float4*)(Qg + gidx + 4 * v);
        runQ[4*v] = qv.x; runQ[4*v+1] = qv.y; runQ[4*v+2] = qv.z; runQ[4*v+3] = qv.w;
    }

    size_t base = (((size_t)(dirb * NCH + grp * GRP)) * DI + d) * 16 + s8 * 8;
    for (int i = 0; i < GRP; i++) {
        size_t idx = base + (size_t)i * (DI * 16);
        f16x8 p8 = *(const f16x8*)(P + idx);
        f16x8 q8 = *(const f16x8*)(Q + idx);
        f16x8 o8;
#pragma unroll
        for (int j = 0; j < 8; j++) {
            o8[j] = (f16)runQ[j];
            runQ[j] = (float)p8[j] * runQ[j] + (float)q8[j];
        }
        *(f16x8*)(Q + idx) = o8;
    }
}

__global__ void k_scan_p3(const float* __restrict__ DBLF, const float* __restrict__ DBLB,
                          const bf16* __restrict__ XSF,  const bf16* __restrict__ XSB,
                          const bf16* __restrict__ XZF,  const bf16* __restrict__ XZB,
                          const float* __restrict__ fWdt, const float* __restrict__ fbdt,
                          const float* __restrict__ bWdt, const float* __restrict__ bbdt,
                          const float* __restrict__ a2tab,
                          const float* __restrict__ fD,    const float* __restrict__ bD,
                          const f16* __restrict__ Q,
                          bf16* __restrict__ YSF, bf16* __restrict__ YSB) {
    int t = blockIdx.x * blockDim.x + threadIdx.x;   // 393216
    int d = t % DI;
    int g = t / DI;
    int chunk = g & (NCH - 1);
    int dirb = g >> 9;
    int b = dirb & 1, dir = dirb >> 1;

    const float* DBL = dir ? DBLB : DBLF;
    const bf16*  XS  = dir ? XSB  : XSF;
    const bf16*  XZ  = dir ? XZB  : XZF;
    const float* wdt = (dir ? bWdt : fWdt) + d * 6;
    float bdtv = (dir ? bbdt : fbdt)[d];
    float Dp = dir ? bD[d] : fD[d];
    bf16* Y = dir ? YSB : YSF;

    float wd[6];
#pragma unroll
    for (int r = 0; r < 6; r++) wd[r] = wdt[r];
    const float* a2p = a2tab + (dir * DI + d) * 16;
    float A2[16], h[16];
#pragma unroll
    for (int v = 0; v < 4; v++) {
        float4 a2v = *(const float4*)(a2p + 4 * v);
        A2[4*v] = a2v.x; A2[4*v+1] = a2v.y; A2[4*v+2] = a2v.z; A2[4*v+3] = a2v.w;
    }
    size_t idx = ((size_t)g * DI + d) * 16;
    f16x8 q0 = *(const f16x8*)(Q + idx);
    f16x8 q1 = *(const f16x8*)(Q + idx + 8);
#pragma unroll
    for (int j = 0; j < 8; j++) { h[j] = (float)q0[j]; h[8 + j] = (float)q1[j]; }

    int l = dir ? (L_SEQ - 1 - chunk * CHUNK) : chunk * CHUNK;
    int stp = dir ? -1 : 1;

    for (int i = 0; i < CHUNK; i++) {
        size_t p = (size_t)b * L_SEQ + l;
        const float* row = DBL + p * LDBL;
        float dtv = bdtv;
#pragma unroll
        for (int r = 0; r < 6; r++) dtv += row[r] * wd[r];
        float del = softplus_f(dtv);
        float xs  = b2f(XS[p * DI + d]);
        float z   = b2f(XZ[p * 384 + 192 + d]);
        const float4* bm = (const float4*)(row + 8);
        float4 B0 = bm[0], B1 = bm[1], B2 = bm[2], B3 = bm[3];
        float4 C0 = bm[4], C1 = bm[5], C2 = bm[6], C3 = bm[7];
        float Bm[16] = {B0.x,B0.y,B0.z,B0.w, B1.x,B1.y,B1.z,B1.w,
                        B2.x,B2.y,B2.z,B2.w, B3.x,B3.y,B3.z,B3.w};
        float Cm[16] = {C0.x,C0.y,C0.z,C0.w, C1.x,C1.y,C1.z,C1.w,
                        C2.x,C2.y,C2.z,C2.w, C3.x,C3.y,C3.z,C3.w};
        float dx = del * xs;
        float pr = 0.f;
#pragma unroll
        for (int s = 0; s < 16; s++) {
            float dA = exp2f(del * A2[s]);
            h[s] = dA * h[s] + dx * Bm[s];
            pr += h[s] * Cm[s];
        }
        Y[p * DI + d] = __float2bfloat16((pr + xs * Dp) * silu_f(z));
        l += stp;
    }
}

// ---------------------------------------------------------------------------
// K9: LDS-tiled mid with inline LN1 recompute:
// x2 = x + gamma1*(yo + ln_cf(x)); XMID planar f32; XM2cl = ln_cf(x2) bf16 cl.
// ---------------------------------------------------------------------------
__global__ void k_mid_t(const float* __restrict__ x, const float* __restrict__ YO,
                        const float* __restrict__ gamma1,
                        const float* __restrict__ ln1w, const float* __restrict__ ln1b,
                        float* __restrict__ XMID, bf16* __restrict__ XM2cl) {
    __shared__ float xt[DIM][TP + 1];
    __shared__ float yt[DIM][TP + 1];
    __shared__ float rs[8][TP], rss[8][TP];
    __shared__ float uu[TP], rr[TP];
    int p0 = blockIdx.x * TP;
    int b = p0 >> 12, l0 = p0 & (L_SEQ - 1);
    int t = threadIdx.x;
    int tg = t >> 5, li = t & 31;

    // load x (planar, coalesced) and YO (channel-last)
    for (int idx = t; idx < DIM * TP; idx += 256) {
        int c = idx >> 5, q = idx & 31;
        xt[c][q] = x[((size_t)(b * DIM + c)) * L_SEQ + l0 + q];
    }
    for (int idx = t; idx < DIM * TP; idx += 256) {
        int q = idx / DIM, c = idx % DIM;
        yt[c][q] = YO[(size_t)(p0 + q) * DIM + c];
    }
    __syncthreads();
    // stats of x (LN1)
    {
        float s = 0.f, ss = 0.f;
        for (int c = tg; c < DIM; c += 8) { float v = xt[c][li]; s += v; ss += v * v; }
        rs[tg][li] = s; rss[tg][li] = ss;
    }
    __syncthreads();
    if (t < TP) {
        float s = 0.f, ss = 0.f;
#pragma unroll
        for (int g = 0; g < 8; g++) { s += rs[g][t]; ss += rss[g][t]; }
        float u = s / DIM;
        uu[t] = u; rr[t] = rsqrtf(ss / DIM - u * u + 1e-6f);
    }
    __syncthreads();
    // v = x + gamma1*(yo + ln1(x)); stats of v
    {
        float u = uu[li], r = rr[li];
        float s = 0.f, ss = 0.f;
        for (int c = tg; c < DIM; c += 8) {
            float xv = xt[c][li];
            float x1 = ln1w[c] * (xv - u) * r + ln1b[c];
            float v = xv + gamma1[c] * (yt[c][li] + x1);
            XMID[((size_t)(b * DIM + c)) * L_SEQ + l0 + li] = v;
            xt[c][li] = v;
            s += v; ss += v * v;
        }
        rs[tg][li] = s; rss[tg][li] = ss;
    }
    __syncthreads();
    if (t < TP) {
        float s = 0.f, ss = 0.f;
#pragma unroll
        for (int g = 0; g < 8; g++) { s += rs[g][t]; ss += rss[g][t]; }
        float u = s / DIM;
        uu[t] = u; rr[t] = rsqrtf(ss / DIM - u * u + 1e-6f);
    }
    __syncthreads();
    for (int idx = t; idx < DIM * TP; idx += 256) {
        int q = idx / DIM, c = idx % DIM;
        XM2cl[(size_t)(p0 + q) * DIM + c] =
            __float2bfloat16(ln1w[c] * (xt[c][q] - uu[q]) * rr[q] + ln1b[c]);
    }
}

// ---------------------------------------------------------------------------
// K11: fused dilated dwconvs + GELU gate, vectorized 8 channels/thread.
// ---------------------------------------------------------------------------
__global__ void k_msff_v(const bf16* __restrict__ H, const float* __restrict__ mdwt,
                         bf16* __restrict__ G) {
    int i = blockIdx.x * blockDim.x + threadIdx.x;   // NPOS*24
    int cg = i % 24;
    int p = i / 24;
    int c0 = cg * 8;
    int b = p >> 12, l = p & (L_SEQ - 1);
    int y = l >> 6, xc = l & 63;
    float a1[8] = {}, a2[8] = {}, a3[8] = {};
    const unsigned short* Hu = (const unsigned short*)H;

#pragma unroll
    for (int ky = 0; ky < 3; ky++) {
#pragma unroll
        for (int kx = 0; kx < 3; kx++) {
            int tap = ky * 3 + kx;
            {
                int y1 = y + (ky - 1), x1 = xc + (kx - 1);
                if (y1 >= 0 && y1 < 64 && x1 >= 0 && x1 < 64) {
                    float4 w0 = *(const float4*)(mdwt + tap * 192 + c0);
                    float4 w1 = *(const float4*)(mdwt + tap * 192 + c0 + 4);
                    ushort8 hv = *(const ushort8*)(Hu +
                        ((size_t)(b * L_SEQ + y1 * 64 + x1)) * 576 + c0);
                    float wv[8] = {w0.x,w0.y,w0.z,w0.w, w1.x,w1.y,w1.z,w1.w};
#pragma unroll
                    for (int j = 0; j < 8; j++) a1[j] += wv[j] * us2f(hv[j]);
                }
            }
            {
                int y2 = y + (ky - 1) * 2, x2 = xc + (kx - 1) * 2;
                if (y2 >= 0 && y2 < 64 && x2 >= 0 && x2 < 64) {
                    float4 w0 = *(const float4*)(mdwt + (9 + tap) * 192 + c0);
                    float4 w1 = *(const float4*)(mdwt + (9 + tap) * 192 + c0 + 4);
                    ushort8 hv = *(const ushort8*)(Hu +
                        ((size_t)(b * L_SEQ + y2 * 64 + x2)) * 576 + 192 + c0);
                    float wv[8] = {w0.x,w0.y,w0.z,w0.w, w1.x,w1.y,w1.z,w1.w};
#pragma unroll
                    for (int j = 0; j < 8; j++) a2[j] += wv[j] * us2f(hv[j]);
                }
            }
            {
                int y3 = y + (ky - 1) * 3, x3 = xc + (kx - 1) * 3;
                if (y3 >= 0 && y3 < 64 && x3 >= 0 && x3 < 64) {
                    float4 w0 = *(const float4*)(mdwt + (18 + tap) * 192 + c0);
                    float4 w1 = *(const float4*)(mdwt + (18 + tap) * 192 + c0 + 4);
                    ushort8 hv = *(const ushort8*)(Hu +
                        ((size_t)(b * L_SEQ + y3 * 64 + x3)) * 576 + 384 + c0);
                    float wv[8] = {w0.x,w0.y,w0.z,w0.w, w1.x,w1.y,w1.z,w1.w};
#pragma unroll
                    for (int j = 0; j < 8; j++) a3[j] += wv[j] * us2f(hv[j]);
                }
            }
        }
    }
    ushort8 ov;
#pragma unroll
    for (int j = 0; j < 8; j++) {
        float ge = 0.5f * a1[j] * (1.f + erff(a1[j] * 0.70710678118f));
        bf16 t = __float2bfloat16(ge * a2[j] * a3[j]);
        ov[j] = *(unsigned short*)&t;
    }
    *(ushort8*)((unsigned short*)G + (size_t)p * HID + c0) = ov;
}

// ---------------------------------------------------------------------------
extern "C" void kernel_launch(void* const* d_in, const int* in_sizes, int n_in,
                              void* d_out, int out_size, void* d_ws, size_t ws_size,
                              hipStream_t stream) {
    const float* x      = (const float*)d_in[0];
    const float* gamma1 = (const float*)d_in[1];
    const float* gamma2 = (const float*)d_in[2];
    const float* ln1w   = (const float*)d_in[3];
    const float* ln1b   = (const float*)d_in[4];
    const float* mnw    = (const float*)d_in[5];
    const float* mnb    = (const float*)d_in[6];
    const float* fWin   = (const float*)d_in[7];
    const float* fconvw = (const float*)d_in[8];
    const float* fconvb = (const float*)d_in[9];
    const float* fWx    = (const float*)d_in[10];
    const float* fWdt   = (const float*)d_in[11];
    const float* fbdt   = (const float*)d_in[12];
    const float* fAlog  = (const float*)d_in[13];
    const float* fD     = (const float*)d_in[14];
    const float* bWin   = (const float*)d_in[15];
    const float* bconvw = (const float*)d_in[16];
    const float* bconvb = (const float*)d_in[17];
    const float* bWx    = (const float*)d_in[18];
    const float* bWdt   = (const float*)d_in[19];
    const float* bbdt   = (const float*)d_in[20];
    const float* bAlog  = (const float*)d_in[21];
    const float* bD     = (const float*)d_in[22];
    const float* Wout   = (const float*)d_in[23];
    const float* mwin   = (const float*)d_in[24];
    const float* mdw1   = (const float*)d_in[25];
    const float* mdw2   = (const float*)d_in[26];
    const float* mdw3   = (const float*)d_in[27];
    const float* mwout  = (const float*)d_in[28];
    float* out = (float*)d_out;

    float* ws = (float*)d_ws;
    // Fully dedicated regions (no overlays). float offsets; total ~77 MB.
    bf16*  XNbf  = (bf16*)(ws);              // 786432 bf16 (393216 f)
    bf16*  XZF   = (bf16*)(ws + 393216);     // 3145728 bf16 (1572864 f)
    bf16*  XZB   = (bf16*)(ws + 1966080);    // 3145728 bf16
    bf16*  XSF   = (bf16*)(ws + 3538944);    // 1572864 bf16 (786432 f)
    bf16*  XSB   = (bf16*)(ws + 4325376);    // 1572864 bf16
    float* DBLF  = ws + 5111808;             // 327680
    float* DBLB  = ws + 5439488;             // 327680
    f16*   Ph    = (f16*)(ws + 5767168);     // 6291456 f16 (3145728 f)
    f16*   Qh    = (f16*)(ws + 8912896);     // 6291456 f16
    bf16*  YSFbf = (bf16*)(ws + 12058624);   // 1572864 bf16
    bf16*  YSBbf = (bf16*)(ws + 12845056);   // 1572864 bf16
    float* YO    = ws + 13631488;            // 786432
    float* XMID  = ws + 14417920;            // 786432
    bf16*  XM2cl = (bf16*)(ws + 15204352);   // 786432 bf16 (393216 f)
    bf16*  Hcl   = (bf16*)(ws + 15597568);   // 4718592 bf16 (2359296 f)
    bf16*  Gcl   = (bf16*)(ws + 17956864);   // 1572864 bf16 (786432 f)
    bf16*  WAR   = (bf16*)(ws + 18743296);   // 180480 bf16 (90240 f)
    float* A2tab = ws + 18833536;            // 6144
    float* MDWT  = ws + 18839680;            // 5184
    float* Pgb   = ws + 18844864;            // 196608 (4*NGRP*DI*16)
    float* Qgb   = ws + 19041472;            // 196608 -> end 19238080 (~77 MB)

    const bf16* fWinB  = WAR;
    const bf16* bWinB  = WAR + 36864;
    const bf16* fWxB   = WAR + 73728;
    const bf16* bWxB   = WAR + 81024;
    const bf16* WoutB  = WAR + 88320;
    const bf16* mwinB  = WAR + 106752;
    const bf16* mwoutB = WAR + 162048;

    // 0. prep
    k_prep<<<750, 256, 0, stream>>>(fWin, bWin, fWx, bWx, Wout, mwin, mwout,
                                    fAlog, bAlog, mdw1, mdw2, mdw3,
                                    WAR, A2tab, MDWT);
    // 1. double LN (LDS-tiled, no X1 store)
    k_ln12_t<<<NPOS / TP, 256, 0, stream>>>(x, ln1w, ln1b, mnw, mnb, XNbf);
    // 2. in-projections, both dirs
    mfma_nt_dir<<<dim3(128, 6, 2), 256, 0, stream>>>(XNbf, XNbf, fWinB, bWinB,
                                                     XZF, XZB, NPOS, 384, DIM, 384, 0, 1);
    // 3. dwconv + silu (vectorized, both dirs)
    k_conv_v<<<dim3(NPOS * 24 / 256, 2), 256, 0, stream>>>(XZF, XZB, fconvw, fconvb,
                                                           bconvw, bconvb, XSF, XSB);
    // 4. x_dbl projections, both dirs (padded LDBL rows)
    mfma_nt_dir<<<dim3(128, 1, 2), 256, 0, stream>>>(XSF, XSB, fWxB, bWxB,
                                                     DBLF, DBLB, NPOS, 38, DI, LDBL, 1, 0);
    // 5-9. chunked parallel scan (CHUNK=8) with hierarchical p2
    k_scan_p1<<<NREC * NCH / 256, 256, 0, stream>>>(DBLF, DBLB, XSF, XSB,
                                                    fWdt, fbdt, bWdt, bbdt,
                                                    A2tab, Ph, Qh);
    k_scan_p2a<<<4 * NGRP * DI * 2 / 256, 256, 0, stream>>>(Ph, Qh, Pgb, Qgb);
    k_scan_p2b<<<NREC * 16 / 256, 256, 0, stream>>>(Pgb, Qgb);
    k_scan_p2c<<<4 * NGRP * DI * 2 / 256, 256, 0, stream>>>(Ph, Qh, Qgb);
    k_scan_p3<<<NREC * NCH / 256, 256, 0, stream>>>(DBLF, DBLB, XSF, XSB, XZF, XZB,
                                                    fWdt, fbdt, bWdt, bbdt,
                                                    A2tab, fD, bD, Qh,
                                                    YSFbf, YSBbf);
    // 10. out-projection (dual-A MFMA, f32 channel-last YO)
    mfma_out<<<dim3(128, 2), 256, 0, stream>>>(YSFbf, YSBbf, WoutB, YO, NPOS, DIM, DI, DIM);
    // 11. residual + LN (LDS-tiled, LN1 recomputed inline)
    k_mid_t<<<NPOS / TP, 256, 0, stream>>>(x, YO, gamma1, ln1w, ln1b, XMID, XM2cl);
    // 12. msff in-projection (MFMA, bf16 channel-last H)
    mfma_nt<<<dim3(128, 9), 256, 0, stream>>>(XM2cl, mwinB, Hcl, NPOS, 576, DIM, 576);
    // 13. fused dilated dwconvs + GELU gate (vectorized)
    k_msff_v<<<NPOS * 24 / 256, 256, 0, stream>>>(Hcl, MDWT, Gcl);
    // 14. msff out-projection + fused final residual -> out
    mfma_msffout<<<dim3(2, 128), 256, 0, stream>>>(mwoutB, Gcl, XMID, gamma2, out, DIM, HID);
}